// Round 7
// baseline (115.399 us; speedup 1.0000x reference)
//
#include <hip/hip_runtime.h>
#include <cstdint>
#include <cstddef>

#define N_ENT 100000
#define DIM 128
#define BSZ 256
#define FSZ 20000
#define BM 64
#define NBT 1563             // ceil(N_ENT / 64) row-blocks; padded rows to NBT*64
#define MCAP 8192

typedef __attribute__((ext_vector_type(8))) short bf16x8;
typedef __attribute__((ext_vector_type(4))) float f32x4;

#define KEEP(x) asm volatile("" : "+v"(x))

// ---------------- ws layout (all offsets 16B-aligned) ----------------
#define WS_QALL  0                                   // [512][128] f32 exact queries
#define WS_QSQ   (512 * DIM * 4)                     // [512] f32
#define WS_THR   (WS_QSQ + 2048)                     // [512] f32
#define WS_THC   (WS_THR + 2048)                     // [512] f32 (thr-qsq)*0.5
#define WS_CNT   (WS_THC + 2048)                     // [512] int (atomic fallback)
#define WS_MCNT  (WS_CNT + 2048)                     // int + pad
#define WS_MATCH (WS_MCNT + 16)                      // [MCAP] int2
#define WS_QBF   (WS_MATCH + MCAP * 8)               // [512][128] bf16 row-major (fallback)
#define WS_QBFP  (WS_QBF + 512 * DIM * 2)            // [32][4][64][8] bf16 fragment-major
#define WS_PART  (WS_QBFP + 512 * DIM * 2)           // [NBT][512] u16
#define WS_ESQH  (WS_PART + NBT * 512 * 2)           // [NBT*64] f32 half-norms (exact)
#define WS_ABF   (WS_ESQH + NBT * 64 * 4)            // [NBT*4][4][64][8] bf16 fragment-major A
#define WS_NEED  (WS_ABF + (size_t)NBT * 64 * DIM * 2)

__device__ inline unsigned short f2bf(float x) {
    union { float f; uint32_t u; } v; v.f = x;
    uint32_t u = v.u;
    u += 0x7fffu + ((u >> 16) & 1);   // RNE
    return (unsigned short)(u >> 16);
}

__global__ __launch_bounds__(128) void k_prep(
    const float* __restrict__ ent, const float* __restrict__ rel,
    const int* __restrict__ heads, const int* __restrict__ rels, const int* __restrict__ tails,
    float* __restrict__ qall, float* __restrict__ qsq, float* __restrict__ thr,
    float* __restrict__ thc, int* __restrict__ cnt, int* __restrict__ mcnt,
    unsigned short* __restrict__ qbf, unsigned short* __restrict__ qbfp)
{
    int b = blockIdx.x;
    int d = threadIdx.x;
    if (b == 0 && d == 0) *mcnt = 0;
    int h = heads[b], r = rels[b], t = tails[b];
    float eh = ent[(size_t)h * DIM + d];
    float er = rel[(size_t)r * DIM + d];
    float et = ent[(size_t)t * DIM + d];
    float diff = eh + er - et;
    float q = er - et;
    float p = eh + er;
    qall[(size_t)b * DIM + d] = q;
    qall[(size_t)(BSZ + b) * DIM + d] = -p;
    unsigned short qb16 = f2bf(q), pb16 = f2bf(-p);
    qbf[(size_t)b * DIM + d] = qb16;
    qbf[(size_t)(BSZ + b) * DIM + d] = pb16;
    // fragment-major: idx = ((c*4+ks)*64 + kq*16 + (col&15))*8 + e
    int ks = d >> 5, kq = (d >> 3) & 3, e = d & 7;
    int l0 = kq * 16 + (b & 15);
    int c0 = b >> 4, c1 = (BSZ + b) >> 4;
    qbfp[(size_t)((c0 * 4 + ks) * 64 + l0) * 8 + e] = qb16;
    qbfp[(size_t)((c1 * 4 + ks) * 64 + l0) * 8 + e] = pb16;

    float s0 = diff * diff, s1 = q * q, s2 = p * p;
    #pragma unroll
    for (int off = 32; off; off >>= 1) {
        s0 += __shfl_xor(s0, off);
        s1 += __shfl_xor(s1, off);
        s2 += __shfl_xor(s2, off);
    }
    __shared__ float part[2][3];
    int wave = threadIdx.x >> 6, lane = threadIdx.x & 63;
    if (lane == 0) { part[wave][0] = s0; part[wave][1] = s1; part[wave][2] = s2; }
    __syncthreads();
    if (threadIdx.x == 0) {
        float tsq = part[0][0] + part[1][0];
        float qq  = part[0][1] + part[1][1];
        float pp  = part[0][2] + part[1][2];
        float th = fmaxf(tsq, 1e-12f);
        thr[b] = th; thr[BSZ + b] = th;
        qsq[b] = qq; qsq[BSZ + b] = pp;
        thc[b] = (th - qq) * 0.5f;
        thc[BSZ + b] = (th - pp) * 0.5f;
        cnt[b] = 0;  cnt[BSZ + b] = 0;
    }
}

__global__ __launch_bounds__(256) void k_scanf(
    const int* __restrict__ heads, const int* __restrict__ rels, const int* __restrict__ tails,
    const int* __restrict__ fh, const int* __restrict__ fr, const int* __restrict__ ft,
    int* __restrict__ mcnt, int2* __restrict__ match)
{
    __shared__ int hh[BSZ], rr[BSZ], tt[BSZ];
    int tid = threadIdx.x;
    hh[tid] = heads[tid]; rr[tid] = rels[tid]; tt[tid] = tails[tid];
    __syncthreads();
    int f = blockIdx.x * 256 + tid;
    if (f >= FSZ) return;
    int vr = fr[f], vt = ft[f], vh = fh[f];
    for (int b = 0; b < BSZ; b++) {
        int rb = rr[b];
        if (vr == rb && vt == tt[b]) {
            int p = atomicAdd(mcnt, 1);
            if (p < MCAP) match[p] = make_int2(b, vh);
        }
        if (vr == rb && vh == hh[b]) {
            int p = atomicAdd(mcnt, 1);
            if (p < MCAP) match[p] = make_int2(BSZ + b, vt);
        }
    }
}

// Pack ent -> abf (MFMA-fragment-major bf16) + exact fp32 half-norms.
// Reads coalesced float4; writes 16B chunks, 16 rows contiguous per wave.
__global__ __launch_bounds__(256) void k_pack(
    const float* __restrict__ ent,
    unsigned short* __restrict__ abf, float* __restrict__ esqh)
{
    int tid = threadIdx.x;
    int row = tid >> 2, qtr = tid & 3;               // 64 rows/block, 4 threads/row
    int np = blockIdx.x * BM + row;                  // padded row index
    bool valid = np < N_ENT;
    const float4* src = (const float4*)(ent + (size_t)(valid ? np : 0) * DIM) + qtr * 8;
    float4 v[8];
    float ss = 0.f;
    #pragma unroll
    for (int j = 0; j < 8; j++) {
        float4 u = src[j];
        v[j] = valid ? u : make_float4(0.f, 0.f, 0.f, 0.f);
        ss += v[j].x * v[j].x + v[j].y * v[j].y + v[j].z * v[j].z + v[j].w * v[j].w;
    }
    ss += __shfl_xor(ss, 1);
    ss += __shfl_xor(ss, 2);
    if (qtr == 0) esqh[np] = valid ? 0.5f * ss : 1.5e38f;
    int t = np >> 4;                                 // global 16-row tile
    #pragma unroll
    for (int m = 0; m < 4; m++) {                    // kq = m
        uint4 w;
        w.x = (uint32_t)f2bf(v[2*m    ].x) | ((uint32_t)f2bf(v[2*m    ].y) << 16);
        w.y = (uint32_t)f2bf(v[2*m    ].z) | ((uint32_t)f2bf(v[2*m    ].w) << 16);
        w.z = (uint32_t)f2bf(v[2*m + 1].x) | ((uint32_t)f2bf(v[2*m + 1].y) << 16);
        w.w = (uint32_t)f2bf(v[2*m + 1].z) | ((uint32_t)f2bf(v[2*m + 1].w) << 16);
        size_t idx = ((size_t)(t * 4 + qtr) * 64 + m * 16 + (row & 15)) * 8;
        *(uint4*)(abf + idx) = w;
    }
}

// MFMA count v4: 1 wave per block, 64 rows x 512 cols. ALL loads are
// lane-contiguous 1KB wave-loads (A & B pre-packed in fragment order).
// esq folded into the MFMA accumulator init; per-lane packed counts;
// single shfl-reduce + 1KB coalesced u16 flush at the end.
__global__ __launch_bounds__(64, 2) void k_count(
    const unsigned short* __restrict__ abf, const float* __restrict__ esqh,
    const unsigned short* __restrict__ qbfp, const float* __restrict__ thc,
    unsigned short* __restrict__ part)
{
    int l = threadIdx.x;
    int bt = blockIdx.x;

    // A: 16 coalesced 1KB loads -> 64 VGPRs
    bf16x8 a[4][4];
    #pragma unroll
    for (int s = 0; s < 4; s++)
        #pragma unroll
        for (int ks = 0; ks < 4; ks++) {
            a[s][ks] = *(const bf16x8*)(abf + ((size_t)((4 * bt + s) * 4 + ks) * 64 + l) * 8);
            KEEP(a[s][ks]);
        }
    // exact half-norms in C layout (row = s*16 + (l>>4)*4 + r)
    f32x4 ehv[4];
    #pragma unroll
    for (int s = 0; s < 4; s++) {
        #pragma unroll
        for (int r = 0; r < 4; r++)
            ehv[s][r] = esqh[bt * BM + s * 16 + (l >> 4) * 4 + r];
        KEEP(ehv[s]);
    }

    // B chunk-0 prefetch (coalesced) + threshold prefetch
    bf16x8 bcur[4], bnext[4];
    #pragma unroll
    for (int ks = 0; ks < 4; ks++)
        bcur[ks] = *(const bf16x8*)(qbfp + ((size_t)ks * 64 + l) * 8);
    float tc = thc[l & 15];
    float tnext;

    uint32_t creg[8] = {0, 0, 0, 0, 0, 0, 0, 0};

    #pragma unroll
    for (int c = 0; c < 32; c++) {
        if (c < 31) {
            #pragma unroll
            for (int ks = 0; ks < 4; ks++)
                bnext[ks] = *(const bf16x8*)(qbfp + ((size_t)((c + 1) * 4 + ks) * 64 + l) * 8);
            tnext = thc[(c + 1) * 16 + (l & 15)];
        }
        f32x4 acc[4];
        #pragma unroll
        for (int s = 0; s < 4; s++)   // esq folded in via C-operand
            acc[s] = __builtin_amdgcn_mfma_f32_16x16x32_bf16(a[s][0], bcur[0], ehv[s], 0, 0, 0);
        #pragma unroll
        for (int ks = 1; ks < 4; ks++)
            #pragma unroll
            for (int s = 0; s < 4; s++)
                acc[s] = __builtin_amdgcn_mfma_f32_16x16x32_bf16(a[s][ks], bcur[ks], acc[s], 0, 0, 0);
        uint32_t cl = 0;
        #pragma unroll
        for (int s = 0; s < 4; s++)
            #pragma unroll
            for (int r = 0; r < 4; r++)
                cl += (acc[s][r] < tc) ? 1u : 0u;   // esqh + dot < (thr-qsq)/2
        creg[c >> 2] += cl << (8 * (c & 3));        // compile-time indices (full unroll)
        tc = tnext;
        #pragma unroll
        for (int ks = 0; ks < 4; ks++) bcur[ks] = bnext[ks];
    }

    // reduce packed bytes across the 4 kq groups (max 4*16=64, no carry)
    #pragma unroll
    for (int i = 0; i < 8; i++) {
        uint32_t x = creg[i];
        x += __shfl_xor(x, 16);
        x += __shfl_xor(x, 32);
        creg[i] = x;
    }
    if (l < 16) {
        #pragma unroll
        for (int c = 0; c < 32; c++)
            part[(size_t)bt * 512 + c * 16 + l] =
                (unsigned short)((creg[c >> 2] >> (8 * (c & 3))) & 0xffu);
    }
}

// Fallback (proven round-6 path) if ws can't hold abf: direct ent reads + atomics.
__global__ __launch_bounds__(128, 3) void k_count_fb(
    const float* __restrict__ ent,
    const unsigned short* __restrict__ qbf,
    const float* __restrict__ thc,
    int* __restrict__ cnt)
{
    int tid = threadIdx.x;
    int lane = tid & 63, wave = tid >> 6;
    int base = blockIdx.x * BM;
    int koff = (lane >> 4) * 8;
    int colq = wave * 256 + (lane & 15);
    const unsigned short* qb = qbf + (size_t)colq * DIM + koff;
    bf16x8 bcur[4], bnext[4];
    #pragma unroll
    for (int ks = 0; ks < 4; ks++) bcur[ks] = *(const bf16x8*)(qb + ks * 32);
    bf16x8 a[4][4];
    float hsq[4];
    #pragma unroll
    for (int s = 0; s < 4; s++) {
        int n = base + s * 16 + (lane & 15);
        bool valid = n < N_ENT;
        const float* rowp = ent + (size_t)(valid ? n : (N_ENT - 1)) * DIM + koff;
        float ss = 0.f;
        #pragma unroll
        for (int ks = 0; ks < 4; ks++) {
            float4 u0 = *(const float4*)(rowp + ks * 32);
            float4 u1 = *(const float4*)(rowp + ks * 32 + 4);
            ss += u0.x*u0.x + u0.y*u0.y + u0.z*u0.z + u0.w*u0.w
                + u1.x*u1.x + u1.y*u1.y + u1.z*u1.z + u1.w*u1.w;
            bf16x8 f;
            f[0]=(short)f2bf(u0.x); f[1]=(short)f2bf(u0.y); f[2]=(short)f2bf(u0.z); f[3]=(short)f2bf(u0.w);
            f[4]=(short)f2bf(u1.x); f[5]=(short)f2bf(u1.y); f[6]=(short)f2bf(u1.z); f[7]=(short)f2bf(u1.w);
            a[s][ks] = f; KEEP(a[s][ks]);
        }
        ss += __shfl_xor(ss, 16); ss += __shfl_xor(ss, 32);
        hsq[s] = valid ? ss * 0.5f : 1.5e38f;
    }
    float eh[4][4];
    #pragma unroll
    for (int s = 0; s < 4; s++)
        #pragma unroll
        for (int r = 0; r < 4; r++) { eh[s][r] = __shfl(hsq[s], (lane >> 4) * 4 + r); KEEP(eh[s][r]); }
    #pragma unroll
    for (int c = 0; c < 16; c++) {
        if (c < 15) {
            #pragma unroll
            for (int ks = 0; ks < 4; ks++)
                bnext[ks] = *(const bf16x8*)(qb + (size_t)(c + 1) * 16 * DIM + ks * 32);
        }
        float tcv = thc[colq + c * 16];
        f32x4 acc[4];
        #pragma unroll
        for (int s = 0; s < 4; s++) acc[s] = (f32x4){0.f, 0.f, 0.f, 0.f};
        #pragma unroll
        for (int ks = 0; ks < 4; ks++)
            #pragma unroll
            for (int s = 0; s < 4; s++)
                acc[s] = __builtin_amdgcn_mfma_f32_16x16x32_bf16(a[s][ks], bcur[ks], acc[s], 0, 0, 0);
        int cl = 0;
        #pragma unroll
        for (int s = 0; s < 4; s++)
            #pragma unroll
            for (int r = 0; r < 4; r++)
                cl += (acc[s][r] < tcv - eh[s][r]) ? 1 : 0;
        cl += __shfl_xor(cl, 16);
        cl += __shfl_xor(cl, 32);
        if (lane < 16) atomicAdd(&cnt[colq + c * 16], cl);
        #pragma unroll
        for (int ks = 0; ks < 4; ks++) bcur[ks] = bnext[ks];
    }
}

__global__ __launch_bounds__(256) void k_adjust(
    const float* __restrict__ ent,
    const float* __restrict__ qall, const float* __restrict__ qsq, const float* __restrict__ thr,
    const int* __restrict__ cnt, const unsigned short* __restrict__ part, int use_part,
    const int* __restrict__ mcnt, const int2* __restrict__ match,
    int* __restrict__ out)
{
    int key = blockIdx.x;
    int tid = threadIdx.x;
    __shared__ int ids[256];
    __shared__ int nm;
    __shared__ int wsum[4];
    if (tid == 0) nm = 0;
    __syncthreads();

    int acc = 0;
    if (use_part) {
        for (int i = tid; i < NBT; i += 256)
            acc += part[(size_t)i * 512 + key];
    } else if (tid == 0) {
        acc = cnt[key];
    }

    int M = *mcnt; if (M > MCAP) M = MCAP;
    for (int i = tid; i < M; i += 256) {
        int2 e = match[i];
        if (e.x == key) { int p = atomicAdd(&nm, 1); if (p < 256) ids[p] = e.y; }
    }
    __syncthreads();
    int mm = nm < 256 ? nm : 256;
    const float* qv = qall + (size_t)key * DIM;
    float qq = qsq[key], th = thr[key];
    for (int i = tid; i < mm; i += 256) {
        int id = ids[i];
        bool dup = false;
        for (int j = 0; j < i; j++) if (ids[j] == id) { dup = true; break; }
        if (!dup) {
            const float* en = ent + (size_t)id * DIM;
            float es = 0.f, dot = 0.f;
            for (int d = 0; d < DIM; d++) { float x = en[d]; es += x * x; dot += x * qv[d]; }
            if (fmaxf(es + 2.f * dot + qq, 1e-12f) < th) acc--;
        }
    }
    #pragma unroll
    for (int off = 32; off; off >>= 1) acc += __shfl_xor(acc, off);
    int lane = tid & 63, wv = tid >> 6;
    if (lane == 0) wsum[wv] = acc;
    __syncthreads();
    if (tid == 0) out[key] = wsum[0] + wsum[1] + wsum[2] + wsum[3] + 1;
}

extern "C" void kernel_launch(void* const* d_in, const int* in_sizes, int n_in,
                              void* d_out, int out_size, void* d_ws, size_t ws_size,
                              hipStream_t stream)
{
    const float* ent   = (const float*)d_in[0];
    const float* rel   = (const float*)d_in[1];
    const int*   heads = (const int*)d_in[2];
    const int*   rels  = (const int*)d_in[3];
    const int*   tails = (const int*)d_in[4];
    const int*   fh    = (const int*)d_in[5];
    const int*   fr    = (const int*)d_in[6];
    const int*   ft    = (const int*)d_in[7];
    int* out = (int*)d_out;

    char* ws = (char*)d_ws;
    float* qall = (float*)(ws + WS_QALL);
    float* qsq  = (float*)(ws + WS_QSQ);
    float* thr  = (float*)(ws + WS_THR);
    float* thc  = (float*)(ws + WS_THC);
    int*   cnt  = (int*)(ws + WS_CNT);
    int*   mcnt = (int*)(ws + WS_MCNT);
    int2*  match = (int2*)(ws + WS_MATCH);
    unsigned short* qbf  = (unsigned short*)(ws + WS_QBF);
    unsigned short* qbfp = (unsigned short*)(ws + WS_QBFP);
    unsigned short* part = (unsigned short*)(ws + WS_PART);
    float* esqh = (float*)(ws + WS_ESQH);
    unsigned short* abf  = (unsigned short*)(ws + WS_ABF);

    int use_part = (ws_size >= (size_t)WS_NEED) ? 1 : 0;

    k_prep<<<BSZ, 128, 0, stream>>>(ent, rel, heads, rels, tails,
                                    qall, qsq, thr, thc, cnt, mcnt, qbf, qbfp);
    k_scanf<<<(FSZ + 255) / 256, 256, 0, stream>>>(heads, rels, tails, fh, fr, ft, mcnt, match);
    if (use_part) {
        k_pack<<<NBT, 256, 0, stream>>>(ent, abf, esqh);
        k_count<<<NBT, 64, 0, stream>>>(abf, esqh, qbfp, thc, part);
    } else {
        k_count_fb<<<NBT, 128, 0, stream>>>(ent, qbf, thc, cnt);
    }
    k_adjust<<<2 * BSZ, 256, 0, stream>>>(ent, qall, qsq, thr, cnt, part, use_part,
                                          mcnt, match, out);
}

// Round 9
// 83.186 us; speedup vs baseline: 1.3872x; 1.3872x over previous
//
#include <hip/hip_runtime.h>
#include <cstdint>
#include <cstddef>

#define N_ENT 100000
#define DIM 128
#define BSZ 256
#define FSZ 20000
#define BM 64
#define NBT 1563             // ceil(N_ENT / 64) row-blocks; rows padded to NPAD
#define NPAD (NBT * 64)      // 100032 padded rows
#define PACK_BLOCKS 391      // ceil(NPAD*32 float4 / 8192 float4-per-block)
#define RG  98               // ceil(NBT / 16) reduce groups
#define MCAP 8192

typedef __attribute__((ext_vector_type(8))) short bf16x8;
typedef __attribute__((ext_vector_type(4))) float f32x4;

#define KEEP(x) asm volatile("" : "+v"(x))

// ---------------- ws layout (16B-aligned offsets) ----------------
#define WS_QALL  0                                   // [512][128] f32 exact queries
#define WS_QSQ   (512 * DIM * 4)                     // [512] f32
#define WS_THR   (WS_QSQ + 2048)                     // [512] f32
#define WS_THC   (WS_THR + 2048)                     // [512] f32 (thr-qsq)*0.5
#define WS_CNT   (WS_THC + 2048)                     // [512] int (atomic fallback)
#define WS_MCNT  (WS_CNT + 2048)                     // int + pad
#define WS_MATCH (WS_MCNT + 16)                      // [MCAP] int2
#define WS_QBF   (WS_MATCH + MCAP * 8)               // [512][128] bf16 row-major (fallback)
#define WS_QBFP  (WS_QBF + 512 * DIM * 2)            // [32][4][64][8] bf16 fragment-major
#define WS_PART  (WS_QBFP + 512 * DIM * 2)           // [NBT][512] u16
#define WS_PART2 (WS_PART + NBT * 512 * 2)           // [RG][512] u16
#define WS_ESQH  (WS_PART2 + RG * 512 * 2)           // [NPAD] f32 half-norms (exact)
#define WS_ABF   (WS_ESQH + NPAD * 4)                // [NBT*4][4][64][8] bf16 fragment-major A
#define WS_NEED  (WS_ABF + (size_t)NPAD * DIM * 2)

__device__ inline unsigned short f2bf(float x) {
    union { float f; uint32_t u; } v; v.f = x;
    uint32_t u = v.u;
    u += 0x7fffu + ((u >> 16) & 1);   // RNE
    return (unsigned short)(u >> 16);
}

__global__ __launch_bounds__(128) void k_prep(
    const float* __restrict__ ent, const float* __restrict__ rel,
    const int* __restrict__ heads, const int* __restrict__ rels, const int* __restrict__ tails,
    float* __restrict__ qall, float* __restrict__ qsq, float* __restrict__ thr,
    float* __restrict__ thc, int* __restrict__ cnt, int* __restrict__ mcnt,
    unsigned short* __restrict__ qbf, unsigned short* __restrict__ qbfp)
{
    int b = blockIdx.x;
    int d = threadIdx.x;
    if (b == 0 && d == 0) *mcnt = 0;
    int h = heads[b], r = rels[b], t = tails[b];
    float eh = ent[(size_t)h * DIM + d];
    float er = rel[(size_t)r * DIM + d];
    float et = ent[(size_t)t * DIM + d];
    float diff = eh + er - et;
    float q = er - et;
    float p = eh + er;
    qall[(size_t)b * DIM + d] = q;
    qall[(size_t)(BSZ + b) * DIM + d] = -p;
    unsigned short qb16 = f2bf(q), pb16 = f2bf(-p);
    qbf[(size_t)b * DIM + d] = qb16;
    qbf[(size_t)(BSZ + b) * DIM + d] = pb16;
    // fragment-major B: idx = ((c*4+ks)*64 + kq*16 + (col&15))*8 + e
    int ks = d >> 5, kq = (d >> 3) & 3, e = d & 7;
    int l0 = kq * 16 + (b & 15);
    int c0 = b >> 4, c1 = (BSZ + b) >> 4;
    qbfp[(size_t)((c0 * 4 + ks) * 64 + l0) * 8 + e] = qb16;
    qbfp[(size_t)((c1 * 4 + ks) * 64 + l0) * 8 + e] = pb16;

    float s0 = diff * diff, s1 = q * q, s2 = p * p;
    #pragma unroll
    for (int off = 32; off; off >>= 1) {
        s0 += __shfl_xor(s0, off);
        s1 += __shfl_xor(s1, off);
        s2 += __shfl_xor(s2, off);
    }
    __shared__ float part[2][3];
    int wave = threadIdx.x >> 6, lane = threadIdx.x & 63;
    if (lane == 0) { part[wave][0] = s0; part[wave][1] = s1; part[wave][2] = s2; }
    __syncthreads();
    if (threadIdx.x == 0) {
        float tsq = part[0][0] + part[1][0];
        float qq  = part[0][1] + part[1][1];
        float pp  = part[0][2] + part[1][2];
        float th = fmaxf(tsq, 1e-12f);
        thr[b] = th; thr[BSZ + b] = th;
        qsq[b] = qq; qsq[BSZ + b] = pp;
        thc[b] = (th - qq) * 0.5f;
        thc[BSZ + b] = (th - pp) * 0.5f;
        cnt[b] = 0;  cnt[BSZ + b] = 0;
    }
}

// Filter scan: combined 32-bit keys (r*100000+x < 2^31) -> 2 LDS reads + 2 cmps.
__global__ __launch_bounds__(256) void k_scanf(
    const int* __restrict__ heads, const int* __restrict__ rels, const int* __restrict__ tails,
    const int* __restrict__ fh, const int* __restrict__ fr, const int* __restrict__ ft,
    int* __restrict__ mcnt, int2* __restrict__ match)
{
    __shared__ int k1[BSZ], k2[BSZ];
    int tid = threadIdx.x;
    k1[tid] = rels[tid] * 100000 + tails[tid];
    k2[tid] = rels[tid] * 100000 + heads[tid];
    __syncthreads();
    int f = blockIdx.x * 256 + tid;
    if (f >= FSZ) return;
    int vr = fr[f], vt = ft[f], vh = fh[f];
    int fk1 = vr * 100000 + vt;   // head-side: (f_rel==r)&(f_tail==t)
    int fk2 = vr * 100000 + vh;   // tail-side: (f_rel==r)&(f_head==h)
    for (int b = 0; b < BSZ; b++) {
        if (fk1 == k1[b]) {
            int p = atomicAdd(mcnt, 1);
            if (p < MCAP) match[p] = make_int2(b, vh);
        }
        if (fk2 == k2[b]) {
            int p = atomicAdd(mcnt, 1);
            if (p < MCAP) match[p] = make_int2(BSZ + b, vt);
        }
    }
}

// Pack ent -> abf (MFMA-fragment-major bf16) + exact fp32 half-norms.
// LANE-CONTIGUOUS reads: thread tid handles float4 (base4 + i*256 + tid) =>
// every wave instruction reads 1KB contiguous. Block = 8192 float4 = 256 rows.
// Grid = PACK_BLOCKS (391) covers exactly NPAD rows; per-iter bound guard.
__global__ __launch_bounds__(256) void k_pack(
    const float* __restrict__ ent,
    unsigned short* __restrict__ abf, float* __restrict__ esqh)
{
    int tid = threadIdx.x;
    int k4 = tid & 31;
    int ks = k4 >> 3, kq = (k4 >> 1) & 3, e0 = (k4 & 1) * 4;
    int base4 = blockIdx.x * 8192;
    #pragma unroll 4
    for (int i = 0; i < 32; i++) {
        int fidx = base4 + i * 256 + tid;
        int np = fidx >> 5;                          // padded row
        if (np >= NPAD) continue;                    // uniform per 32-lane row group
        bool valid = np < N_ENT;
        float4 u = make_float4(0.f, 0.f, 0.f, 0.f);
        if (valid) u = ((const float4*)ent)[fidx];
        float ss = u.x * u.x + u.y * u.y + u.z * u.z + u.w * u.w;
        ss += __shfl_xor(ss, 1);
        ss += __shfl_xor(ss, 2);
        ss += __shfl_xor(ss, 4);
        ss += __shfl_xor(ss, 8);
        ss += __shfl_xor(ss, 16);
        if (k4 == 0) esqh[np] = valid ? 0.5f * ss : 1.5e38f;
        uint2 w;
        w.x = (uint32_t)f2bf(u.x) | ((uint32_t)f2bf(u.y) << 16);
        w.y = (uint32_t)f2bf(u.z) | ((uint32_t)f2bf(u.w) << 16);
        int t = np >> 4;
        size_t idx = ((size_t)(t * 4 + ks) * 64 + kq * 16 + (np & 15)) * 8 + e0;
        *(uint2*)(abf + idx) = w;
    }
}

// MFMA count: 1 wave/block, 64 rows x 512 cols, all loads 1KB lane-contiguous,
// 2-deep B prefetch, esq folded into accumulator init, packed register counts,
// one coalesced 1KB u16 flush.
__global__ __launch_bounds__(64, 3) void k_count(
    const unsigned short* __restrict__ abf, const float* __restrict__ esqh,
    const unsigned short* __restrict__ qbfp, const float* __restrict__ thc,
    unsigned short* __restrict__ part)
{
    int l = threadIdx.x;
    int bt = blockIdx.x;

    bf16x8 a[4][4];
    #pragma unroll
    for (int s = 0; s < 4; s++)
        #pragma unroll
        for (int ks = 0; ks < 4; ks++) {
            a[s][ks] = *(const bf16x8*)(abf + ((size_t)((4 * bt + s) * 4 + ks) * 64 + l) * 8);
            KEEP(a[s][ks]);
        }
    f32x4 ehv[4];
    #pragma unroll
    for (int s = 0; s < 4; s++) {
        #pragma unroll
        for (int r = 0; r < 4; r++)
            ehv[s][r] = esqh[bt * BM + s * 16 + (l >> 4) * 4 + r];
        KEEP(ehv[s]);
    }

    bf16x8 bcur[4], bn1[4], bn2[4];
    #pragma unroll
    for (int ks = 0; ks < 4; ks++) {
        bcur[ks] = *(const bf16x8*)(qbfp + ((size_t)(0 * 4 + ks) * 64 + l) * 8);
        bn1[ks]  = *(const bf16x8*)(qbfp + ((size_t)(1 * 4 + ks) * 64 + l) * 8);
    }
    float tc  = thc[l & 15];
    float tn1 = thc[16 + (l & 15)];
    float tn2;

    uint32_t creg[8] = {0, 0, 0, 0, 0, 0, 0, 0};

    #pragma unroll
    for (int c = 0; c < 32; c++) {
        if (c < 30) {
            #pragma unroll
            for (int ks = 0; ks < 4; ks++)
                bn2[ks] = *(const bf16x8*)(qbfp + ((size_t)((c + 2) * 4 + ks) * 64 + l) * 8);
            tn2 = thc[(c + 2) * 16 + (l & 15)];
        }
        f32x4 acc[4];
        #pragma unroll
        for (int s = 0; s < 4; s++)   // esq enters via the C operand
            acc[s] = __builtin_amdgcn_mfma_f32_16x16x32_bf16(a[s][0], bcur[0], ehv[s], 0, 0, 0);
        #pragma unroll
        for (int ks = 1; ks < 4; ks++)
            #pragma unroll
            for (int s = 0; s < 4; s++)
                acc[s] = __builtin_amdgcn_mfma_f32_16x16x32_bf16(a[s][ks], bcur[ks], acc[s], 0, 0, 0);
        uint32_t cl = 0;
        #pragma unroll
        for (int s = 0; s < 4; s++)
            #pragma unroll
            for (int r = 0; r < 4; r++)
                cl += (acc[s][r] < tc) ? 1u : 0u;   // esqh + dot < (thr-qsq)/2
        creg[c >> 2] += cl << (8 * (c & 3));
        tc = tn1; tn1 = tn2;
        #pragma unroll
        for (int ks = 0; ks < 4; ks++) { bcur[ks] = bn1[ks]; bn1[ks] = bn2[ks]; }
    }

    #pragma unroll
    for (int i = 0; i < 8; i++) {
        uint32_t x = creg[i];
        x += __shfl_xor(x, 16);
        x += __shfl_xor(x, 32);
        creg[i] = x;
    }
    if (l < 16) {
        #pragma unroll
        for (int c = 0; c < 32; c++)
            part[(size_t)bt * 512 + c * 16 + l] =
                (unsigned short)((creg[c >> 2] >> (8 * (c & 3))) & 0xffu);
    }
}

// Stage-1 reduce: 16 part rows -> 1, fully coalesced u32 reads/writes.
__global__ __launch_bounds__(256) void k_reduce(
    const unsigned short* __restrict__ part, unsigned short* __restrict__ part2)
{
    int g = blockIdx.x, tid = threadIdx.x;
    int r0 = g * 16, r1 = r0 + 16 < NBT ? r0 + 16 : NBT;
    uint32_t lo = 0, hi = 0;
    for (int r = r0; r < r1; r++) {
        uint32_t v = *(const uint32_t*)(part + (size_t)r * 512 + tid * 2);
        lo += v & 0xffffu;
        hi += v >> 16;
    }
    *(uint32_t*)(part2 + (size_t)g * 512 + tid * 2) = lo | (hi << 16);
}

// Fallback path (round-6 proven) when ws can't hold abf.
__global__ __launch_bounds__(128, 3) void k_count_fb(
    const float* __restrict__ ent,
    const unsigned short* __restrict__ qbf,
    const float* __restrict__ thc,
    int* __restrict__ cnt)
{
    int tid = threadIdx.x;
    int lane = tid & 63, wave = tid >> 6;
    int base = blockIdx.x * BM;
    int koff = (lane >> 4) * 8;
    int colq = wave * 256 + (lane & 15);
    const unsigned short* qb = qbf + (size_t)colq * DIM + koff;
    bf16x8 bcur[4], bnext[4];
    #pragma unroll
    for (int ks = 0; ks < 4; ks++) bcur[ks] = *(const bf16x8*)(qb + ks * 32);
    bf16x8 a[4][4];
    float hsq[4];
    #pragma unroll
    for (int s = 0; s < 4; s++) {
        int n = base + s * 16 + (lane & 15);
        bool valid = n < N_ENT;
        const float* rowp = ent + (size_t)(valid ? n : (N_ENT - 1)) * DIM + koff;
        float ss = 0.f;
        #pragma unroll
        for (int ks = 0; ks < 4; ks++) {
            float4 u0 = *(const float4*)(rowp + ks * 32);
            float4 u1 = *(const float4*)(rowp + ks * 32 + 4);
            ss += u0.x*u0.x + u0.y*u0.y + u0.z*u0.z + u0.w*u0.w
                + u1.x*u1.x + u1.y*u1.y + u1.z*u1.z + u1.w*u1.w;
            bf16x8 f;
            f[0]=(short)f2bf(u0.x); f[1]=(short)f2bf(u0.y); f[2]=(short)f2bf(u0.z); f[3]=(short)f2bf(u0.w);
            f[4]=(short)f2bf(u1.x); f[5]=(short)f2bf(u1.y); f[6]=(short)f2bf(u1.z); f[7]=(short)f2bf(u1.w);
            a[s][ks] = f; KEEP(a[s][ks]);
        }
        ss += __shfl_xor(ss, 16); ss += __shfl_xor(ss, 32);
        hsq[s] = valid ? ss * 0.5f : 1.5e38f;
    }
    float eh[4][4];
    #pragma unroll
    for (int s = 0; s < 4; s++)
        #pragma unroll
        for (int r = 0; r < 4; r++) { eh[s][r] = __shfl(hsq[s], (lane >> 4) * 4 + r); KEEP(eh[s][r]); }
    #pragma unroll
    for (int c = 0; c < 16; c++) {
        if (c < 15) {
            #pragma unroll
            for (int ks = 0; ks < 4; ks++)
                bnext[ks] = *(const bf16x8*)(qb + (size_t)(c + 1) * 16 * DIM + ks * 32);
        }
        float tcv = thc[colq + c * 16];
        f32x4 acc[4];
        #pragma unroll
        for (int s = 0; s < 4; s++) acc[s] = (f32x4){0.f, 0.f, 0.f, 0.f};
        #pragma unroll
        for (int ks = 0; ks < 4; ks++)
            #pragma unroll
            for (int s = 0; s < 4; s++)
                acc[s] = __builtin_amdgcn_mfma_f32_16x16x32_bf16(a[s][ks], bcur[ks], acc[s], 0, 0, 0);
        int cl = 0;
        #pragma unroll
        for (int s = 0; s < 4; s++)
            #pragma unroll
            for (int r = 0; r < 4; r++)
                cl += (acc[s][r] < tcv - eh[s][r]) ? 1 : 0;
        cl += __shfl_xor(cl, 16);
        cl += __shfl_xor(cl, 32);
        if (lane < 16) atomicAdd(&cnt[colq + c * 16], cl);
        #pragma unroll
        for (int ks = 0; ks < 4; ks++) bcur[ks] = bnext[ks];
    }
}

__global__ __launch_bounds__(256) void k_adjust(
    const float* __restrict__ ent,
    const float* __restrict__ qall, const float* __restrict__ qsq, const float* __restrict__ thr,
    const int* __restrict__ cnt, const unsigned short* __restrict__ part2, int use_part,
    const int* __restrict__ mcnt, const int2* __restrict__ match,
    int* __restrict__ out)
{
    int key = blockIdx.x;
    int tid = threadIdx.x;
    __shared__ int ids[256];
    __shared__ int nm;
    __shared__ int wsum[4];
    if (tid == 0) nm = 0;
    __syncthreads();

    int acc = 0;
    if (use_part) {
        if (tid < RG) acc = part2[(size_t)tid * 512 + key];
    } else if (tid == 0) {
        acc = cnt[key];
    }

    int M = *mcnt; if (M > MCAP) M = MCAP;
    for (int i = tid; i < M; i += 256) {
        int2 e = match[i];
        if (e.x == key) { int p = atomicAdd(&nm, 1); if (p < 256) ids[p] = e.y; }
    }
    __syncthreads();
    int mm = nm < 256 ? nm : 256;
    const float* qv = qall + (size_t)key * DIM;
    float qq = qsq[key], th = thr[key];
    for (int i = tid; i < mm; i += 256) {
        int id = ids[i];
        bool dup = false;
        for (int j = 0; j < i; j++) if (ids[j] == id) { dup = true; break; }
        if (!dup) {
            const float* en = ent + (size_t)id * DIM;
            float es = 0.f, dot = 0.f;
            for (int d = 0; d < DIM; d++) { float x = en[d]; es += x * x; dot += x * qv[d]; }
            if (fmaxf(es + 2.f * dot + qq, 1e-12f) < th) acc--;
        }
    }
    #pragma unroll
    for (int off = 32; off; off >>= 1) acc += __shfl_xor(acc, off);
    int lane = tid & 63, wv = tid >> 6;
    if (lane == 0) wsum[wv] = acc;
    __syncthreads();
    if (tid == 0) out[key] = wsum[0] + wsum[1] + wsum[2] + wsum[3] + 1;
}

extern "C" void kernel_launch(void* const* d_in, const int* in_sizes, int n_in,
                              void* d_out, int out_size, void* d_ws, size_t ws_size,
                              hipStream_t stream)
{
    const float* ent   = (const float*)d_in[0];
    const float* rel   = (const float*)d_in[1];
    const int*   heads = (const int*)d_in[2];
    const int*   rels  = (const int*)d_in[3];
    const int*   tails = (const int*)d_in[4];
    const int*   fh    = (const int*)d_in[5];
    const int*   fr    = (const int*)d_in[6];
    const int*   ft    = (const int*)d_in[7];
    int* out = (int*)d_out;

    char* ws = (char*)d_ws;
    float* qall = (float*)(ws + WS_QALL);
    float* qsq  = (float*)(ws + WS_QSQ);
    float* thr  = (float*)(ws + WS_THR);
    float* thc  = (float*)(ws + WS_THC);
    int*   cnt  = (int*)(ws + WS_CNT);
    int*   mcnt = (int*)(ws + WS_MCNT);
    int2*  match = (int2*)(ws + WS_MATCH);
    unsigned short* qbf   = (unsigned short*)(ws + WS_QBF);
    unsigned short* qbfp  = (unsigned short*)(ws + WS_QBFP);
    unsigned short* part  = (unsigned short*)(ws + WS_PART);
    unsigned short* part2 = (unsigned short*)(ws + WS_PART2);
    float* esqh = (float*)(ws + WS_ESQH);
    unsigned short* abf  = (unsigned short*)(ws + WS_ABF);

    int use_part = (ws_size >= (size_t)WS_NEED) ? 1 : 0;

    k_prep<<<BSZ, 128, 0, stream>>>(ent, rel, heads, rels, tails,
                                    qall, qsq, thr, thc, cnt, mcnt, qbf, qbfp);
    k_scanf<<<(FSZ + 255) / 256, 256, 0, stream>>>(heads, rels, tails, fh, fr, ft, mcnt, match);
    if (use_part) {
        k_pack<<<PACK_BLOCKS, 256, 0, stream>>>(ent, abf, esqh);
        k_count<<<NBT, 64, 0, stream>>>(abf, esqh, qbfp, thc, part);
        k_reduce<<<RG, 256, 0, stream>>>(part, part2);
    } else {
        k_count_fb<<<NBT, 128, 0, stream>>>(ent, qbf, thc, cnt);
    }
    k_adjust<<<2 * BSZ, 256, 0, stream>>>(ent, qall, qsq, thr, cnt, part2, use_part,
                                          mcnt, match, out);
}

// Round 10
// 73.721 us; speedup vs baseline: 1.5653x; 1.1284x over previous
//
#include <hip/hip_runtime.h>
#include <cstdint>
#include <cstddef>

#define N_ENT 100000
#define DIM 128
#define BSZ 256
#define FSZ 20000
#define BM 64
#define NBT 1563             // ceil(N_ENT / 64) row-blocks; rows padded to NPAD
#define NPAD (NBT * 64)      // 100032 padded rows
#define RG  98               // ceil(NBT / 16) reduce groups
#define MCAP 8192

typedef __attribute__((ext_vector_type(8))) short bf16x8;
typedef __attribute__((ext_vector_type(4))) float f32x4;

#define KEEP(x) asm volatile("" : "+v"(x))

// ---------------- ws layout (16B-aligned offsets) ----------------
#define WS_QALL  0                                   // [512][128] f32 exact queries
#define WS_QSQ   (512 * DIM * 4)                     // [512] f32
#define WS_THR   (WS_QSQ + 2048)                     // [512] f32
#define WS_THC   (WS_THR + 2048)                     // [512] f32 (thr-qsq)*0.5
#define WS_CNT   (WS_THC + 2048)                     // [512] int (atomic fallback)
#define WS_MCNT  (WS_CNT + 2048)                     // int + pad
#define WS_MATCH (WS_MCNT + 16)                      // [MCAP] int2
#define WS_QBF   (WS_MATCH + MCAP * 8)               // [512][128] bf16 row-major (fallback)
#define WS_QBFP  (WS_QBF + 512 * DIM * 2)            // [32][4][64][8] bf16 fragment-major
#define WS_PART  (WS_QBFP + 512 * DIM * 2)           // [NBT][512] u16
#define WS_PART2 (WS_PART + NBT * 512 * 2)           // [RG][512] u16
#define WS_ESQH  (WS_PART2 + RG * 512 * 2)           // [NPAD] f32 half-norms (exact)
#define WS_ABF   (WS_ESQH + NPAD * 4)                // [NBT*4][4][64][8] bf16 fragment-major A
#define WS_NEED  (WS_ABF + (size_t)NPAD * DIM * 2)

__device__ inline unsigned short f2bf(float x) {
    union { float f; uint32_t u; } v; v.f = x;
    uint32_t u = v.u;
    u += 0x7fffu + ((u >> 16) & 1);   // RNE
    return (unsigned short)(u >> 16);
}

__global__ __launch_bounds__(128) void k_prep(
    const float* __restrict__ ent, const float* __restrict__ rel,
    const int* __restrict__ heads, const int* __restrict__ rels, const int* __restrict__ tails,
    float* __restrict__ qall, float* __restrict__ qsq, float* __restrict__ thr,
    float* __restrict__ thc, int* __restrict__ cnt, int* __restrict__ mcnt,
    unsigned short* __restrict__ qbf, unsigned short* __restrict__ qbfp)
{
    int b = blockIdx.x;
    int d = threadIdx.x;
    if (b == 0 && d == 0) *mcnt = 0;
    int h = heads[b], r = rels[b], t = tails[b];
    float eh = ent[(size_t)h * DIM + d];
    float er = rel[(size_t)r * DIM + d];
    float et = ent[(size_t)t * DIM + d];
    float diff = eh + er - et;
    float q = er - et;
    float p = eh + er;
    qall[(size_t)b * DIM + d] = q;
    qall[(size_t)(BSZ + b) * DIM + d] = -p;
    unsigned short qb16 = f2bf(q), pb16 = f2bf(-p);
    qbf[(size_t)b * DIM + d] = qb16;
    qbf[(size_t)(BSZ + b) * DIM + d] = pb16;
    // fragment-major B: idx = ((c*4+ks)*64 + kq*16 + (col&15))*8 + e
    int ks = d >> 5, kq = (d >> 3) & 3, e = d & 7;
    int l0 = kq * 16 + (b & 15);
    int c0 = b >> 4, c1 = (BSZ + b) >> 4;
    qbfp[(size_t)((c0 * 4 + ks) * 64 + l0) * 8 + e] = qb16;
    qbfp[(size_t)((c1 * 4 + ks) * 64 + l0) * 8 + e] = pb16;

    float s0 = diff * diff, s1 = q * q, s2 = p * p;
    #pragma unroll
    for (int off = 32; off; off >>= 1) {
        s0 += __shfl_xor(s0, off);
        s1 += __shfl_xor(s1, off);
        s2 += __shfl_xor(s2, off);
    }
    __shared__ float part[2][3];
    int wave = threadIdx.x >> 6, lane = threadIdx.x & 63;
    if (lane == 0) { part[wave][0] = s0; part[wave][1] = s1; part[wave][2] = s2; }
    __syncthreads();
    if (threadIdx.x == 0) {
        float tsq = part[0][0] + part[1][0];
        float qq  = part[0][1] + part[1][1];
        float pp  = part[0][2] + part[1][2];
        float th = fmaxf(tsq, 1e-12f);
        thr[b] = th; thr[BSZ + b] = th;
        qsq[b] = qq; qsq[BSZ + b] = pp;
        thc[b] = (th - qq) * 0.5f;
        thc[BSZ + b] = (th - pp) * 0.5f;
        cnt[b] = 0;  cnt[BSZ + b] = 0;
    }
}

// Inverted filter scan: one block per b, threads stream F coalesced.
// Two register keys per block; 3 coalesced loads + 2 compares per iter.
__global__ __launch_bounds__(256) void k_scanf(
    const int* __restrict__ heads, const int* __restrict__ rels, const int* __restrict__ tails,
    const int* __restrict__ fh, const int* __restrict__ fr, const int* __restrict__ ft,
    int* __restrict__ mcnt, int2* __restrict__ match)
{
    int b = blockIdx.x;
    int k1b = rels[b] * 100000 + tails[b];   // head-side: (f_rel==r)&(f_tail==t)
    int k2b = rels[b] * 100000 + heads[b];   // tail-side: (f_rel==r)&(f_head==h)
    for (int f = threadIdx.x; f < FSZ; f += 256) {
        int vr = fr[f], vt = ft[f], vh = fh[f];
        int fk1 = vr * 100000 + vt;
        int fk2 = vr * 100000 + vh;
        if (fk1 == k1b) {
            int p = atomicAdd(mcnt, 1);
            if (p < MCAP) match[p] = make_int2(b, vh);
        }
        if (fk2 == k2b) {
            int p = atomicAdd(mcnt, 1);
            if (p < MCAP) match[p] = make_int2(BSZ + b, vt);
        }
    }
}

// Pack ent -> abf (MFMA-fragment-major bf16) + exact fp32 half-norms.
// Lane-contiguous 1KB wave reads; 1563 blocks x 8 iters (24 waves/CU TLP).
__global__ __launch_bounds__(256) void k_pack(
    const float* __restrict__ ent,
    unsigned short* __restrict__ abf, float* __restrict__ esqh)
{
    int tid = threadIdx.x;
    int k4 = tid & 31;
    int ks = k4 >> 3, kq = (k4 >> 1) & 3, e0 = (k4 & 1) * 4;
    int base4 = blockIdx.x * 2048;               // block = 64 rows = 2048 float4
    #pragma unroll
    for (int i = 0; i < 8; i++) {
        int fidx = base4 + i * 256 + tid;
        int np = fidx >> 5;                      // padded row < NPAD by construction
        bool valid = np < N_ENT;
        float4 u = make_float4(0.f, 0.f, 0.f, 0.f);
        if (valid) u = ((const float4*)ent)[fidx];
        float ss = u.x * u.x + u.y * u.y + u.z * u.z + u.w * u.w;
        ss += __shfl_xor(ss, 1);
        ss += __shfl_xor(ss, 2);
        ss += __shfl_xor(ss, 4);
        ss += __shfl_xor(ss, 8);
        ss += __shfl_xor(ss, 16);
        if (k4 == 0) esqh[np] = valid ? 0.5f * ss : 1.5e38f;
        uint2 w;
        w.x = (uint32_t)f2bf(u.x) | ((uint32_t)f2bf(u.y) << 16);
        w.y = (uint32_t)f2bf(u.z) | ((uint32_t)f2bf(u.w) << 16);
        int t = np >> 4;
        size_t idx = ((size_t)(t * 4 + ks) * 64 + kq * 16 + (np & 15)) * 8 + e0;
        *(uint2*)(abf + idx) = w;
    }
}

// MFMA count: 4-wave blocks, wave w owns row-tile bt = blockIdx*4 + w.
// Co-scheduled waves read the SAME B stream => L1 hits cut L2 B-traffic 4x.
// Per-wave structure unchanged: all loads 1KB lane-contiguous, 2-deep B
// prefetch, esq folded into accumulator init, packed register counts.
__global__ __launch_bounds__(256, 2) void k_count(
    const unsigned short* __restrict__ abf, const float* __restrict__ esqh,
    const unsigned short* __restrict__ qbfp, const float* __restrict__ thc,
    unsigned short* __restrict__ part)
{
    int tid = threadIdx.x;
    int l = tid & 63;
    int bt = blockIdx.x * 4 + (tid >> 6);
    if (bt >= NBT) return;

    bf16x8 a[4][4];
    #pragma unroll
    for (int s = 0; s < 4; s++)
        #pragma unroll
        for (int ks = 0; ks < 4; ks++) {
            a[s][ks] = *(const bf16x8*)(abf + ((size_t)((4 * bt + s) * 4 + ks) * 64 + l) * 8);
            KEEP(a[s][ks]);
        }
    f32x4 ehv[4];
    #pragma unroll
    for (int s = 0; s < 4; s++) {
        #pragma unroll
        for (int r = 0; r < 4; r++)
            ehv[s][r] = esqh[bt * BM + s * 16 + (l >> 4) * 4 + r];
        KEEP(ehv[s]);
    }

    bf16x8 bcur[4], bn1[4], bn2[4];
    #pragma unroll
    for (int ks = 0; ks < 4; ks++) {
        bcur[ks] = *(const bf16x8*)(qbfp + ((size_t)(0 * 4 + ks) * 64 + l) * 8);
        bn1[ks]  = *(const bf16x8*)(qbfp + ((size_t)(1 * 4 + ks) * 64 + l) * 8);
    }
    float tc  = thc[l & 15];
    float tn1 = thc[16 + (l & 15)];
    float tn2;

    uint32_t creg[8] = {0, 0, 0, 0, 0, 0, 0, 0};

    #pragma unroll
    for (int c = 0; c < 32; c++) {
        if (c < 30) {
            #pragma unroll
            for (int ks = 0; ks < 4; ks++)
                bn2[ks] = *(const bf16x8*)(qbfp + ((size_t)((c + 2) * 4 + ks) * 64 + l) * 8);
            tn2 = thc[(c + 2) * 16 + (l & 15)];
        }
        f32x4 acc[4];
        #pragma unroll
        for (int s = 0; s < 4; s++)   // esq enters via the C operand
            acc[s] = __builtin_amdgcn_mfma_f32_16x16x32_bf16(a[s][0], bcur[0], ehv[s], 0, 0, 0);
        #pragma unroll
        for (int ks = 1; ks < 4; ks++)
            #pragma unroll
            for (int s = 0; s < 4; s++)
                acc[s] = __builtin_amdgcn_mfma_f32_16x16x32_bf16(a[s][ks], bcur[ks], acc[s], 0, 0, 0);
        uint32_t cl = 0;
        #pragma unroll
        for (int s = 0; s < 4; s++)
            #pragma unroll
            for (int r = 0; r < 4; r++)
                cl += (acc[s][r] < tc) ? 1u : 0u;   // esqh + dot < (thr-qsq)/2
        creg[c >> 2] += cl << (8 * (c & 3));
        tc = tn1; tn1 = tn2;
        #pragma unroll
        for (int ks = 0; ks < 4; ks++) { bcur[ks] = bn1[ks]; bn1[ks] = bn2[ks]; }
    }

    #pragma unroll
    for (int i = 0; i < 8; i++) {
        uint32_t x = creg[i];
        x += __shfl_xor(x, 16);
        x += __shfl_xor(x, 32);
        creg[i] = x;
    }
    if (l < 16) {
        #pragma unroll
        for (int c = 0; c < 32; c++)
            part[(size_t)bt * 512 + c * 16 + l] =
                (unsigned short)((creg[c >> 2] >> (8 * (c & 3))) & 0xffu);
    }
}

// Stage-1 reduce: 16 part rows -> 1, fully coalesced u32 reads/writes.
__global__ __launch_bounds__(256) void k_reduce(
    const unsigned short* __restrict__ part, unsigned short* __restrict__ part2)
{
    int g = blockIdx.x, tid = threadIdx.x;
    int r0 = g * 16, r1 = r0 + 16 < NBT ? r0 + 16 : NBT;
    uint32_t lo = 0, hi = 0;
    for (int r = r0; r < r1; r++) {
        uint32_t v = *(const uint32_t*)(part + (size_t)r * 512 + tid * 2);
        lo += v & 0xffffu;
        hi += v >> 16;
    }
    *(uint32_t*)(part2 + (size_t)g * 512 + tid * 2) = lo | (hi << 16);
}

// Fallback path (round-6 proven) when ws can't hold abf.
__global__ __launch_bounds__(128, 3) void k_count_fb(
    const float* __restrict__ ent,
    const unsigned short* __restrict__ qbf,
    const float* __restrict__ thc,
    int* __restrict__ cnt)
{
    int tid = threadIdx.x;
    int lane = tid & 63, wave = tid >> 6;
    int base = blockIdx.x * BM;
    int koff = (lane >> 4) * 8;
    int colq = wave * 256 + (lane & 15);
    const unsigned short* qb = qbf + (size_t)colq * DIM + koff;
    bf16x8 bcur[4], bnext[4];
    #pragma unroll
    for (int ks = 0; ks < 4; ks++) bcur[ks] = *(const bf16x8*)(qb + ks * 32);
    bf16x8 a[4][4];
    float hsq[4];
    #pragma unroll
    for (int s = 0; s < 4; s++) {
        int n = base + s * 16 + (lane & 15);
        bool valid = n < N_ENT;
        const float* rowp = ent + (size_t)(valid ? n : (N_ENT - 1)) * DIM + koff;
        float ss = 0.f;
        #pragma unroll
        for (int ks = 0; ks < 4; ks++) {
            float4 u0 = *(const float4*)(rowp + ks * 32);
            float4 u1 = *(const float4*)(rowp + ks * 32 + 4);
            ss += u0.x*u0.x + u0.y*u0.y + u0.z*u0.z + u0.w*u0.w
                + u1.x*u1.x + u1.y*u1.y + u1.z*u1.z + u1.w*u1.w;
            bf16x8 f;
            f[0]=(short)f2bf(u0.x); f[1]=(short)f2bf(u0.y); f[2]=(short)f2bf(u0.z); f[3]=(short)f2bf(u0.w);
            f[4]=(short)f2bf(u1.x); f[5]=(short)f2bf(u1.y); f[6]=(short)f2bf(u1.z); f[7]=(short)f2bf(u1.w);
            a[s][ks] = f; KEEP(a[s][ks]);
        }
        ss += __shfl_xor(ss, 16); ss += __shfl_xor(ss, 32);
        hsq[s] = valid ? ss * 0.5f : 1.5e38f;
    }
    float eh[4][4];
    #pragma unroll
    for (int s = 0; s < 4; s++)
        #pragma unroll
        for (int r = 0; r < 4; r++) { eh[s][r] = __shfl(hsq[s], (lane >> 4) * 4 + r); KEEP(eh[s][r]); }
    #pragma unroll
    for (int c = 0; c < 16; c++) {
        if (c < 15) {
            #pragma unroll
            for (int ks = 0; ks < 4; ks++)
                bnext[ks] = *(const bf16x8*)(qb + (size_t)(c + 1) * 16 * DIM + ks * 32);
        }
        float tcv = thc[colq + c * 16];
        f32x4 acc[4];
        #pragma unroll
        for (int s = 0; s < 4; s++) acc[s] = (f32x4){0.f, 0.f, 0.f, 0.f};
        #pragma unroll
        for (int ks = 0; ks < 4; ks++)
            #pragma unroll
            for (int s = 0; s < 4; s++)
                acc[s] = __builtin_amdgcn_mfma_f32_16x16x32_bf16(a[s][ks], bcur[ks], acc[s], 0, 0, 0);
        int cl = 0;
        #pragma unroll
        for (int s = 0; s < 4; s++)
            #pragma unroll
            for (int r = 0; r < 4; r++)
                cl += (acc[s][r] < tcv - eh[s][r]) ? 1 : 0;
        cl += __shfl_xor(cl, 16);
        cl += __shfl_xor(cl, 32);
        if (lane < 16) atomicAdd(&cnt[colq + c * 16], cl);
        #pragma unroll
        for (int ks = 0; ks < 4; ks++) bcur[ks] = bnext[ks];
    }
}

__global__ __launch_bounds__(256) void k_adjust(
    const float* __restrict__ ent,
    const float* __restrict__ qall, const float* __restrict__ qsq, const float* __restrict__ thr,
    const int* __restrict__ cnt, const unsigned short* __restrict__ part2, int use_part,
    const int* __restrict__ mcnt, const int2* __restrict__ match,
    int* __restrict__ out)
{
    int key = blockIdx.x;
    int tid = threadIdx.x;
    __shared__ int ids[256];
    __shared__ int nm;
    __shared__ int wsum[4];
    if (tid == 0) nm = 0;
    __syncthreads();

    int acc = 0;
    if (use_part) {
        if (tid < RG) acc = part2[(size_t)tid * 512 + key];
    } else if (tid == 0) {
        acc = cnt[key];
    }

    int M = *mcnt; if (M > MCAP) M = MCAP;
    for (int i = tid; i < M; i += 256) {
        int2 e = match[i];
        if (e.x == key) { int p = atomicAdd(&nm, 1); if (p < 256) ids[p] = e.y; }
    }
    __syncthreads();
    int mm = nm < 256 ? nm : 256;
    const float* qv = qall + (size_t)key * DIM;
    float qq = qsq[key], th = thr[key];
    for (int i = tid; i < mm; i += 256) {
        int id = ids[i];
        bool dup = false;
        for (int j = 0; j < i; j++) if (ids[j] == id) { dup = true; break; }
        if (!dup) {
            const float* en = ent + (size_t)id * DIM;
            float es = 0.f, dot = 0.f;
            for (int d = 0; d < DIM; d++) { float x = en[d]; es += x * x; dot += x * qv[d]; }
            if (fmaxf(es + 2.f * dot + qq, 1e-12f) < th) acc--;
        }
    }
    #pragma unroll
    for (int off = 32; off; off >>= 1) acc += __shfl_xor(acc, off);
    int lane = tid & 63, wv = tid >> 6;
    if (lane == 0) wsum[wv] = acc;
    __syncthreads();
    if (tid == 0) out[key] = wsum[0] + wsum[1] + wsum[2] + wsum[3] + 1;
}

extern "C" void kernel_launch(void* const* d_in, const int* in_sizes, int n_in,
                              void* d_out, int out_size, void* d_ws, size_t ws_size,
                              hipStream_t stream)
{
    const float* ent   = (const float*)d_in[0];
    const float* rel   = (const float*)d_in[1];
    const int*   heads = (const int*)d_in[2];
    const int*   rels  = (const int*)d_in[3];
    const int*   tails = (const int*)d_in[4];
    const int*   fh    = (const int*)d_in[5];
    const int*   fr    = (const int*)d_in[6];
    const int*   ft    = (const int*)d_in[7];
    int* out = (int*)d_out;

    char* ws = (char*)d_ws;
    float* qall = (float*)(ws + WS_QALL);
    float* qsq  = (float*)(ws + WS_QSQ);
    float* thr  = (float*)(ws + WS_THR);
    float* thc  = (float*)(ws + WS_THC);
    int*   cnt  = (int*)(ws + WS_CNT);
    int*   mcnt = (int*)(ws + WS_MCNT);
    int2*  match = (int2*)(ws + WS_MATCH);
    unsigned short* qbf   = (unsigned short*)(ws + WS_QBF);
    unsigned short* qbfp  = (unsigned short*)(ws + WS_QBFP);
    unsigned short* part  = (unsigned short*)(ws + WS_PART);
    unsigned short* part2 = (unsigned short*)(ws + WS_PART2);
    float* esqh = (float*)(ws + WS_ESQH);
    unsigned short* abf  = (unsigned short*)(ws + WS_ABF);

    int use_part = (ws_size >= (size_t)WS_NEED) ? 1 : 0;

    k_prep<<<BSZ, 128, 0, stream>>>(ent, rel, heads, rels, tails,
                                    qall, qsq, thr, thc, cnt, mcnt, qbf, qbfp);
    k_scanf<<<BSZ, 256, 0, stream>>>(heads, rels, tails, fh, fr, ft, mcnt, match);
    if (use_part) {
        k_pack<<<NBT, 256, 0, stream>>>(ent, abf, esqh);
        k_count<<<(NBT + 3) / 4, 256, 0, stream>>>(abf, esqh, qbfp, thc, part);
        k_reduce<<<RG, 256, 0, stream>>>(part, part2);
    } else {
        k_count_fb<<<NBT, 128, 0, stream>>>(ent, qbf, thc, cnt);
    }
    k_adjust<<<2 * BSZ, 256, 0, stream>>>(ent, qall, qsq, thr, cnt, part2, use_part,
                                          mcnt, match, out);
}

// Round 11
// 62.422 us; speedup vs baseline: 1.8487x; 1.1810x over previous
//
#include <hip/hip_runtime.h>
#include <cstdint>
#include <cstddef>

#define N_ENT 100000
#define DIM 128
#define BSZ 256
#define FSZ 20000
#define BM 64
#define NBT 1563             // ceil(N_ENT / 64) row-blocks; rows padded to NPAD
#define NPAD (NBT * 64)      // 100032 padded rows
#define MCAP_B 64            // per-b match segment capacity

typedef __attribute__((ext_vector_type(8))) short bf16x8;
typedef __attribute__((ext_vector_type(4))) float f32x4;

#define KEEP(x) asm volatile("" : "+v"(x))

// ---------------- ws layout (16B-aligned offsets) ----------------
#define WS_QALL   0                                  // [512][128] f32 exact queries
#define WS_QSQ    262144                             // [512] f32
#define WS_THR    264192                             // [512] f32
#define WS_THC    266240                             // [512] f32 (thr-qsq)*0.5
#define WS_CNT    268288                             // [512] int (atomic fallback)
#define WS_PERCNT 270336                             // [256] int per-b match counts
#define WS_MATCH  271360                             // [256][MCAP_B] int2 {side, id}
#define WS_QBF    402432                             // [512][128] bf16 row-major (fallback)
#define WS_QBFP   533504                             // [32][4][64][8] bf16 fragment-major
#define WS_PART   664576                             // [NBT][512] u16
#define WS_ESQH   2265088                            // [NPAD] f32 half-norms (exact)
#define WS_ABF    2665216                            // [NBT*4][4][64][8] bf16 fragment-major A
#define WS_NEED   (WS_ABF + (size_t)NPAD * DIM * 2)  // ~28.3 MB

__device__ inline unsigned short f2bf(float x) {
    union { float f; uint32_t u; } v; v.f = x;
    uint32_t u = v.u;
    u += 0x7fffu + ((u >> 16) & 1);   // RNE
    return (unsigned short)(u >> 16);
}

// ---- fused front kernel: [0,NBT) pack | [NBT,NBT+256) prep | [+256) scanf ----
__global__ __launch_bounds__(256) void k_front(
    const float* __restrict__ ent, const float* __restrict__ rel,
    const int* __restrict__ heads, const int* __restrict__ rels, const int* __restrict__ tails,
    const int* __restrict__ fh, const int* __restrict__ fr, const int* __restrict__ ft,
    float* __restrict__ qall, float* __restrict__ qsq, float* __restrict__ thr,
    float* __restrict__ thc, int* __restrict__ cnt,
    unsigned short* __restrict__ qbf, unsigned short* __restrict__ qbfp,
    unsigned short* __restrict__ abf, float* __restrict__ esqh,
    int* __restrict__ percnt, int2* __restrict__ match)
{
    int bid = blockIdx.x;
    int tid = threadIdx.x;

    if (bid < NBT) {
        // ---------------- pack: ent -> abf + esqh (lane-contiguous reads) ----
        int k4 = tid & 31;
        int ks = k4 >> 3, kq = (k4 >> 1) & 3, e0 = (k4 & 1) * 4;
        int base4 = bid * 2048;                  // block = 64 rows = 2048 float4
        #pragma unroll
        for (int i = 0; i < 8; i++) {
            int fidx = base4 + i * 256 + tid;
            int np = fidx >> 5;
            bool valid = np < N_ENT;
            float4 u = make_float4(0.f, 0.f, 0.f, 0.f);
            if (valid) u = ((const float4*)ent)[fidx];
            float ss = u.x * u.x + u.y * u.y + u.z * u.z + u.w * u.w;
            ss += __shfl_xor(ss, 1);
            ss += __shfl_xor(ss, 2);
            ss += __shfl_xor(ss, 4);
            ss += __shfl_xor(ss, 8);
            ss += __shfl_xor(ss, 16);
            if (k4 == 0) esqh[np] = valid ? 0.5f * ss : 1.5e38f;
            uint2 w;
            w.x = (uint32_t)f2bf(u.x) | ((uint32_t)f2bf(u.y) << 16);
            w.y = (uint32_t)f2bf(u.z) | ((uint32_t)f2bf(u.w) << 16);
            int t = np >> 4;
            size_t idx = ((size_t)(t * 4 + ks) * 64 + kq * 16 + (np & 15)) * 8 + e0;
            *(uint2*)(abf + idx) = w;
        }
        return;
    }

    if (bid < NBT + BSZ) {
        // ---------------- prep: single wave, lane owns dims d and d+64 -------
        if (tid >= 64) return;                   // no barriers below: safe
        int b = bid - NBT;
        int h = heads[b], r = rels[b], t = tails[b];
        float s0 = 0.f, s1 = 0.f, s2 = 0.f;
        #pragma unroll
        for (int half = 0; half < 2; half++) {
            int d = tid + half * 64;
            float eh = ent[(size_t)h * DIM + d];
            float er = rel[(size_t)r * DIM + d];
            float et = ent[(size_t)t * DIM + d];
            float diff = eh + er - et;
            float q = er - et;
            float p = eh + er;
            qall[(size_t)b * DIM + d] = q;
            qall[(size_t)(BSZ + b) * DIM + d] = -p;
            unsigned short qb16 = f2bf(q), pb16 = f2bf(-p);
            qbf[(size_t)b * DIM + d] = qb16;
            qbf[(size_t)(BSZ + b) * DIM + d] = pb16;
            int ks = d >> 5, kq = (d >> 3) & 3, e = d & 7;
            int l0 = kq * 16 + (b & 15);
            int c0 = b >> 4, c1 = (BSZ + b) >> 4;
            qbfp[(size_t)((c0 * 4 + ks) * 64 + l0) * 8 + e] = qb16;
            qbfp[(size_t)((c1 * 4 + ks) * 64 + l0) * 8 + e] = pb16;
            s0 += diff * diff; s1 += q * q; s2 += p * p;
        }
        #pragma unroll
        for (int off = 32; off; off >>= 1) {
            s0 += __shfl_xor(s0, off);
            s1 += __shfl_xor(s1, off);
            s2 += __shfl_xor(s2, off);
        }
        if (tid == 0) {
            float th = fmaxf(s0, 1e-12f);
            thr[b] = th; thr[BSZ + b] = th;
            qsq[b] = s1; qsq[BSZ + b] = s2;
            thc[b] = (th - s1) * 0.5f;
            thc[BSZ + b] = (th - s2) * 0.5f;
            cnt[b] = 0;  cnt[BSZ + b] = 0;
        }
        return;
    }

    // ---------------- scanf: one block per b, per-b match segment ------------
    {
        int b = bid - NBT - BSZ;
        __shared__ int nm;
        if (tid == 0) nm = 0;
        __syncthreads();                          // uniform: all 256 threads here
        int k1b = rels[b] * 100000 + tails[b];    // head-side key
        int k2b = rels[b] * 100000 + heads[b];    // tail-side key
        for (int f = tid; f < FSZ; f += 256) {
            int vr = fr[f], vt = ft[f], vh = fh[f];
            int fk1 = vr * 100000 + vt;
            int fk2 = vr * 100000 + vh;
            if (fk1 == k1b) {
                int p = atomicAdd(&nm, 1);
                if (p < MCAP_B) match[b * MCAP_B + p] = make_int2(0, vh);
            }
            if (fk2 == k2b) {
                int p = atomicAdd(&nm, 1);
                if (p < MCAP_B) match[b * MCAP_B + p] = make_int2(1, vt);
            }
        }
        __syncthreads();
        if (tid == 0) percnt[b] = nm < MCAP_B ? nm : MCAP_B;
    }
}

// MFMA count: 4-wave blocks, wave w owns row-tile bt = blockIdx*4 + w.
// Co-scheduled waves share the B stream via L1. All loads 1KB lane-contiguous,
// 2-deep B prefetch, esq folded into accumulator init, packed register counts.
__global__ __launch_bounds__(256, 2) void k_count(
    const unsigned short* __restrict__ abf, const float* __restrict__ esqh,
    const unsigned short* __restrict__ qbfp, const float* __restrict__ thc,
    unsigned short* __restrict__ part)
{
    int tid = threadIdx.x;
    int l = tid & 63;
    int bt = blockIdx.x * 4 + (tid >> 6);
    if (bt >= NBT) return;

    bf16x8 a[4][4];
    #pragma unroll
    for (int s = 0; s < 4; s++)
        #pragma unroll
        for (int ks = 0; ks < 4; ks++) {
            a[s][ks] = *(const bf16x8*)(abf + ((size_t)((4 * bt + s) * 4 + ks) * 64 + l) * 8);
            KEEP(a[s][ks]);
        }
    f32x4 ehv[4];
    #pragma unroll
    for (int s = 0; s < 4; s++) {
        #pragma unroll
        for (int r = 0; r < 4; r++)
            ehv[s][r] = esqh[bt * BM + s * 16 + (l >> 4) * 4 + r];
        KEEP(ehv[s]);
    }

    bf16x8 bcur[4], bn1[4], bn2[4];
    #pragma unroll
    for (int ks = 0; ks < 4; ks++) {
        bcur[ks] = *(const bf16x8*)(qbfp + ((size_t)(0 * 4 + ks) * 64 + l) * 8);
        bn1[ks]  = *(const bf16x8*)(qbfp + ((size_t)(1 * 4 + ks) * 64 + l) * 8);
    }
    float tc  = thc[l & 15];
    float tn1 = thc[16 + (l & 15)];
    float tn2;

    uint32_t creg[8] = {0, 0, 0, 0, 0, 0, 0, 0};

    #pragma unroll
    for (int c = 0; c < 32; c++) {
        if (c < 30) {
            #pragma unroll
            for (int ks = 0; ks < 4; ks++)
                bn2[ks] = *(const bf16x8*)(qbfp + ((size_t)((c + 2) * 4 + ks) * 64 + l) * 8);
            tn2 = thc[(c + 2) * 16 + (l & 15)];
        }
        f32x4 acc[4];
        #pragma unroll
        for (int s = 0; s < 4; s++)   // esq enters via the C operand
            acc[s] = __builtin_amdgcn_mfma_f32_16x16x32_bf16(a[s][0], bcur[0], ehv[s], 0, 0, 0);
        #pragma unroll
        for (int ks = 1; ks < 4; ks++)
            #pragma unroll
            for (int s = 0; s < 4; s++)
                acc[s] = __builtin_amdgcn_mfma_f32_16x16x32_bf16(a[s][ks], bcur[ks], acc[s], 0, 0, 0);
        uint32_t cl = 0;
        #pragma unroll
        for (int s = 0; s < 4; s++)
            #pragma unroll
            for (int r = 0; r < 4; r++)
                cl += (acc[s][r] < tc) ? 1u : 0u;   // esqh + dot < (thr-qsq)/2
        creg[c >> 2] += cl << (8 * (c & 3));
        tc = tn1; tn1 = tn2;
        #pragma unroll
        for (int ks = 0; ks < 4; ks++) { bcur[ks] = bn1[ks]; bn1[ks] = bn2[ks]; }
    }

    #pragma unroll
    for (int i = 0; i < 8; i++) {
        uint32_t x = creg[i];
        x += __shfl_xor(x, 16);
        x += __shfl_xor(x, 32);
        creg[i] = x;
    }
    if (l < 16) {
        #pragma unroll
        for (int c = 0; c < 32; c++)
            part[(size_t)bt * 512 + c * 16 + l] =
                (unsigned short)((creg[c >> 2] >> (8 * (c & 3))) & 0xffu);
    }
}

// Fallback path (round-6 proven) when ws can't hold abf.
__global__ __launch_bounds__(128, 3) void k_count_fb(
    const float* __restrict__ ent,
    const unsigned short* __restrict__ qbf,
    const float* __restrict__ thc,
    int* __restrict__ cnt)
{
    int tid = threadIdx.x;
    int lane = tid & 63, wave = tid >> 6;
    int base = blockIdx.x * BM;
    int koff = (lane >> 4) * 8;
    int colq = wave * 256 + (lane & 15);
    const unsigned short* qb = qbf + (size_t)colq * DIM + koff;
    bf16x8 bcur[4], bnext[4];
    #pragma unroll
    for (int ks = 0; ks < 4; ks++) bcur[ks] = *(const bf16x8*)(qb + ks * 32);
    bf16x8 a[4][4];
    float hsq[4];
    #pragma unroll
    for (int s = 0; s < 4; s++) {
        int n = base + s * 16 + (lane & 15);
        bool valid = n < N_ENT;
        const float* rowp = ent + (size_t)(valid ? n : (N_ENT - 1)) * DIM + koff;
        float ss = 0.f;
        #pragma unroll
        for (int ks = 0; ks < 4; ks++) {
            float4 u0 = *(const float4*)(rowp + ks * 32);
            float4 u1 = *(const float4*)(rowp + ks * 32 + 4);
            ss += u0.x*u0.x + u0.y*u0.y + u0.z*u0.z + u0.w*u0.w
                + u1.x*u1.x + u1.y*u1.y + u1.z*u1.z + u1.w*u1.w;
            bf16x8 f;
            f[0]=(short)f2bf(u0.x); f[1]=(short)f2bf(u0.y); f[2]=(short)f2bf(u0.z); f[3]=(short)f2bf(u0.w);
            f[4]=(short)f2bf(u1.x); f[5]=(short)f2bf(u1.y); f[6]=(short)f2bf(u1.z); f[7]=(short)f2bf(u1.w);
            a[s][ks] = f; KEEP(a[s][ks]);
        }
        ss += __shfl_xor(ss, 16); ss += __shfl_xor(ss, 32);
        hsq[s] = valid ? ss * 0.5f : 1.5e38f;
    }
    float eh[4][4];
    #pragma unroll
    for (int s = 0; s < 4; s++)
        #pragma unroll
        for (int r = 0; r < 4; r++) { eh[s][r] = __shfl(hsq[s], (lane >> 4) * 4 + r); KEEP(eh[s][r]); }
    #pragma unroll
    for (int c = 0; c < 16; c++) {
        if (c < 15) {
            #pragma unroll
            for (int ks = 0; ks < 4; ks++)
                bnext[ks] = *(const bf16x8*)(qb + (size_t)(c + 1) * 16 * DIM + ks * 32);
        }
        float tcv = thc[colq + c * 16];
        f32x4 acc[4];
        #pragma unroll
        for (int s = 0; s < 4; s++) acc[s] = (f32x4){0.f, 0.f, 0.f, 0.f};
        #pragma unroll
        for (int ks = 0; ks < 4; ks++)
            #pragma unroll
            for (int s = 0; s < 4; s++)
                acc[s] = __builtin_amdgcn_mfma_f32_16x16x32_bf16(a[s][ks], bcur[ks], acc[s], 0, 0, 0);
        int cl = 0;
        #pragma unroll
        for (int s = 0; s < 4; s++)
            #pragma unroll
            for (int r = 0; r < 4; r++)
                cl += (acc[s][r] < tcv - eh[s][r]) ? 1 : 0;
        cl += __shfl_xor(cl, 16);
        cl += __shfl_xor(cl, 32);
        if (lane < 16) atomicAdd(&cnt[colq + c * 16], cl);
        #pragma unroll
        for (int ks = 0; ks < 4; ks++) bcur[ks] = bnext[ks];
    }
}

// Per (side,b)=key: direct strided sum of the part column (L2-hot), per-b
// match segment gather, dedup, exact fp32 recompute, rank = sum + 1 - adj.
__global__ __launch_bounds__(256) void k_adjust(
    const float* __restrict__ ent,
    const float* __restrict__ qall, const float* __restrict__ qsq, const float* __restrict__ thr,
    const int* __restrict__ cnt, const unsigned short* __restrict__ part, int use_part,
    const int* __restrict__ percnt, const int2* __restrict__ match,
    int* __restrict__ out)
{
    int key = blockIdx.x;
    int side = key >> 8, b = key & 255;
    int tid = threadIdx.x;
    __shared__ int ids[MCAP_B];
    __shared__ int nm;
    __shared__ int wsum[4];
    if (tid == 0) nm = 0;
    __syncthreads();

    int acc = 0;
    if (use_part) {
        for (int i = tid; i < NBT; i += 256)
            acc += part[(size_t)i * 512 + key];
    } else if (tid == 0) {
        acc = cnt[key];
    }

    int M = percnt[b];
    if (tid < M) {
        int2 e = match[b * MCAP_B + tid];
        if (e.x == side) { int p = atomicAdd(&nm, 1); ids[p] = e.y; }
    }
    __syncthreads();
    int mm = nm;
    const float* qv = qall + (size_t)key * DIM;
    float qq = qsq[key], th = thr[key];
    for (int i = tid; i < mm; i += 256) {
        int id = ids[i];
        bool dup = false;
        for (int j = 0; j < i; j++) if (ids[j] == id) { dup = true; break; }
        if (!dup) {
            const float* en = ent + (size_t)id * DIM;
            float es = 0.f, dot = 0.f;
            for (int d = 0; d < DIM; d++) { float x = en[d]; es += x * x; dot += x * qv[d]; }
            if (fmaxf(es + 2.f * dot + qq, 1e-12f) < th) acc--;
        }
    }
    #pragma unroll
    for (int off = 32; off; off >>= 1) acc += __shfl_xor(acc, off);
    int lane = tid & 63, wv = tid >> 6;
    if (lane == 0) wsum[wv] = acc;
    __syncthreads();
    if (tid == 0) out[key] = wsum[0] + wsum[1] + wsum[2] + wsum[3] + 1;
}

extern "C" void kernel_launch(void* const* d_in, const int* in_sizes, int n_in,
                              void* d_out, int out_size, void* d_ws, size_t ws_size,
                              hipStream_t stream)
{
    const float* ent   = (const float*)d_in[0];
    const float* rel   = (const float*)d_in[1];
    const int*   heads = (const int*)d_in[2];
    const int*   rels  = (const int*)d_in[3];
    const int*   tails = (const int*)d_in[4];
    const int*   fh    = (const int*)d_in[5];
    const int*   fr    = (const int*)d_in[6];
    const int*   ft    = (const int*)d_in[7];
    int* out = (int*)d_out;

    char* ws = (char*)d_ws;
    float* qall = (float*)(ws + WS_QALL);
    float* qsq  = (float*)(ws + WS_QSQ);
    float* thr  = (float*)(ws + WS_THR);
    float* thc  = (float*)(ws + WS_THC);
    int*   cnt  = (int*)(ws + WS_CNT);
    int*   percnt = (int*)(ws + WS_PERCNT);
    int2*  match  = (int2*)(ws + WS_MATCH);
    unsigned short* qbf   = (unsigned short*)(ws + WS_QBF);
    unsigned short* qbfp  = (unsigned short*)(ws + WS_QBFP);
    unsigned short* part  = (unsigned short*)(ws + WS_PART);
    float* esqh = (float*)(ws + WS_ESQH);
    unsigned short* abf  = (unsigned short*)(ws + WS_ABF);

    int use_part = (ws_size >= (size_t)WS_NEED) ? 1 : 0;

    k_front<<<NBT + 2 * BSZ, 256, 0, stream>>>(ent, rel, heads, rels, tails, fh, fr, ft,
                                               qall, qsq, thr, thc, cnt, qbf, qbfp,
                                               abf, esqh, percnt, match);
    if (use_part)
        k_count<<<(NBT + 3) / 4, 256, 0, stream>>>(abf, esqh, qbfp, thc, part);
    else
        k_count_fb<<<NBT, 128, 0, stream>>>(ent, qbf, thc, cnt);
    k_adjust<<<2 * BSZ, 256, 0, stream>>>(ent, qall, qsq, thr, cnt, part, use_part,
                                          percnt, match, out);
}

// Round 12
// 58.041 us; speedup vs baseline: 1.9882x; 1.0755x over previous
//
#include <hip/hip_runtime.h>
#include <cstdint>
#include <cstddef>

#define N_ENT 100000
#define DIM 128
#define BSZ 256
#define FSZ 20000
#define BM 64
#define NBT 1563             // ceil(N_ENT / 64) row-tiles
#define MCAP_B 64            // per-b match segment capacity

typedef __attribute__((ext_vector_type(8))) short bf16x8;
typedef __attribute__((ext_vector_type(4))) float f32x4;

#define KEEP(x) asm volatile("" : "+v"(x))

// ---------------- ws layout (16B-aligned offsets) ----------------
#define WS_QALL   0                                  // [512][128] f32 exact queries
#define WS_QSQ    262144                             // [512] f32
#define WS_THR    264192                             // [512] f32
#define WS_THC    266240                             // [512] f32 (thr-qsq)*0.5
#define WS_CNT    268288                             // [512] int (atomic fallback)
#define WS_PERCNT 270336                             // [256] int per-b match counts
#define WS_MATCH  271360                             // [256][MCAP_B] int2 {side, id}
#define WS_QBF    402432                             // [512][128] bf16 row-major (fallback)
#define WS_QBFP   533504                             // [32][4][64][8] bf16 fragment-major
#define WS_PART   664576                             // [NBT][512] u16
#define WS_NEED   (WS_PART + NBT * 512 * 2)          // ~2.3 MB

__device__ inline unsigned short f2bf(float x) {
    union { float f; uint32_t u; } v; v.f = x;
    uint32_t u = v.u;
    u += 0x7fffu + ((u >> 16) & 1);   // RNE
    return (unsigned short)(u >> 16);
}

// ---- fused front kernel: [0,256) scanf | [256,512) prep --------------------
__global__ __launch_bounds__(256) void k_front(
    const float* __restrict__ ent, const float* __restrict__ rel,
    const int* __restrict__ heads, const int* __restrict__ rels, const int* __restrict__ tails,
    const int* __restrict__ fh, const int* __restrict__ fr, const int* __restrict__ ft,
    float* __restrict__ qall, float* __restrict__ qsq, float* __restrict__ thr,
    float* __restrict__ thc, int* __restrict__ cnt,
    unsigned short* __restrict__ qbf, unsigned short* __restrict__ qbfp,
    int* __restrict__ percnt, int2* __restrict__ match)
{
    int bid = blockIdx.x;
    int tid = threadIdx.x;

    if (bid < BSZ) {
        // ---------------- scanf: one block per b, per-b match segment --------
        int b = bid;
        __shared__ int nm;
        if (tid == 0) nm = 0;
        __syncthreads();
        int k1b = rels[b] * 100000 + tails[b];    // head-side key (r,t)
        int k2b = rels[b] * 100000 + heads[b];    // tail-side key (r,h)
        for (int f = tid; f < FSZ; f += 256) {
            int vr = fr[f], vt = ft[f], vh = fh[f];
            int fk1 = vr * 100000 + vt;
            int fk2 = vr * 100000 + vh;
            if (fk1 == k1b) {
                int p = atomicAdd(&nm, 1);
                if (p < MCAP_B) match[b * MCAP_B + p] = make_int2(0, vh);
            }
            if (fk2 == k2b) {
                int p = atomicAdd(&nm, 1);
                if (p < MCAP_B) match[b * MCAP_B + p] = make_int2(1, vt);
            }
        }
        __syncthreads();
        if (tid == 0) percnt[b] = nm < MCAP_B ? nm : MCAP_B;
        return;
    }

    // ---------------- prep: single wave, lane owns dims d and d+64 -----------
    if (tid >= 64) return;                        // no barriers below: safe
    int b = bid - BSZ;
    int h = heads[b], r = rels[b], t = tails[b];
    float s0 = 0.f, s1 = 0.f, s2 = 0.f;
    #pragma unroll
    for (int half = 0; half < 2; half++) {
        int d = tid + half * 64;
        float eh = ent[(size_t)h * DIM + d];
        float er = rel[(size_t)r * DIM + d];
        float et = ent[(size_t)t * DIM + d];
        float diff = eh + er - et;
        float q = er - et;
        float p = eh + er;
        qall[(size_t)b * DIM + d] = q;
        qall[(size_t)(BSZ + b) * DIM + d] = -p;
        unsigned short qb16 = f2bf(q), pb16 = f2bf(-p);
        qbf[(size_t)b * DIM + d] = qb16;
        qbf[(size_t)(BSZ + b) * DIM + d] = pb16;
        int ks = d >> 5, kq = (d >> 3) & 3, e = d & 7;
        int l0 = kq * 16 + (b & 15);
        int c0 = b >> 4, c1 = (BSZ + b) >> 4;
        qbfp[(size_t)((c0 * 4 + ks) * 64 + l0) * 8 + e] = qb16;
        qbfp[(size_t)((c1 * 4 + ks) * 64 + l0) * 8 + e] = pb16;
        s0 += diff * diff; s1 += q * q; s2 += p * p;
    }
    #pragma unroll
    for (int off = 32; off; off >>= 1) {
        s0 += __shfl_xor(s0, off);
        s1 += __shfl_xor(s1, off);
        s2 += __shfl_xor(s2, off);
    }
    if (tid == 0) {
        float th = fmaxf(s0, 1e-12f);
        thr[b] = th; thr[BSZ + b] = th;
        qsq[b] = s1; qsq[BSZ + b] = s2;
        thc[b] = (th - s1) * 0.5f;
        thc[BSZ + b] = (th - s2) * 0.5f;
        cnt[b] = 0;  cnt[BSZ + b] = 0;
    }
}

// MFMA count: 4-wave blocks, wave w owns row-tile bt = blockIdx*4 + w.
// A loaded DIRECTLY from ent (16 rows x 2 float4 per fragment; each CL fully
// covered across lanes), esq via shfl-combine + shfl-redistribute, folded into
// the accumulator init. B streamed from fragment-major qbfp (lane-contiguous,
// L1-shared across the 4 waves), 2-deep prefetch. Packed register counts,
// one coalesced 1KB u16 flush per wave.
__global__ __launch_bounds__(256, 2) void k_count(
    const float* __restrict__ ent,
    const unsigned short* __restrict__ qbfp, const float* __restrict__ thc,
    unsigned short* __restrict__ part)
{
    int tid = threadIdx.x;
    int l = tid & 63;
    int bt = blockIdx.x * 4 + (tid >> 6);
    if (bt >= NBT) return;
    int koff = (l >> 4) * 8;                 // k-quarter owned by this lane

    bf16x8 a[4][4];
    float hsq[4];
    #pragma unroll
    for (int s = 0; s < 4; s++) {
        int n = bt * BM + s * 16 + (l & 15);
        bool valid = n < N_ENT;
        const float* rowp = ent + (size_t)(valid ? n : (N_ENT - 1)) * DIM + koff;
        float ss = 0.f;
        #pragma unroll
        for (int ks = 0; ks < 4; ks++) {
            float4 u0 = *(const float4*)(rowp + ks * 32);
            float4 u1 = *(const float4*)(rowp + ks * 32 + 4);
            ss += u0.x*u0.x + u0.y*u0.y + u0.z*u0.z + u0.w*u0.w
                + u1.x*u1.x + u1.y*u1.y + u1.z*u1.z + u1.w*u1.w;
            bf16x8 f;
            f[0]=(short)f2bf(u0.x); f[1]=(short)f2bf(u0.y); f[2]=(short)f2bf(u0.z); f[3]=(short)f2bf(u0.w);
            f[4]=(short)f2bf(u1.x); f[5]=(short)f2bf(u1.y); f[6]=(short)f2bf(u1.z); f[7]=(short)f2bf(u1.w);
            a[s][ks] = f;
        }
        ss += __shfl_xor(ss, 16);
        ss += __shfl_xor(ss, 32);
        hsq[s] = valid ? ss * 0.5f : 1.5e38f;   // 0.5*||row||^2, inf for pad rows
    }
    // redistribute to C layout: lane needs rows s*16 + (l>>4)*4 + r
    f32x4 ehv[4];
    #pragma unroll
    for (int s = 0; s < 4; s++)
        #pragma unroll
        for (int r = 0; r < 4; r++)
            ehv[s][r] = __shfl(hsq[s], (l >> 4) * 4 + r);

    bf16x8 bcur[4], bn1[4], bn2[4];
    #pragma unroll
    for (int ks = 0; ks < 4; ks++) {
        bcur[ks] = *(const bf16x8*)(qbfp + ((size_t)(0 * 4 + ks) * 64 + l) * 8);
        bn1[ks]  = *(const bf16x8*)(qbfp + ((size_t)(1 * 4 + ks) * 64 + l) * 8);
    }
    float tc  = thc[l & 15];
    float tn1 = thc[16 + (l & 15)];
    float tn2;

    uint32_t creg[8] = {0, 0, 0, 0, 0, 0, 0, 0};

    #pragma unroll
    for (int c = 0; c < 32; c++) {
        // free liveness tie: forbids rematerializing a[]/ehv[] from memory
        #pragma unroll
        for (int s = 0; s < 4; s++) {
            KEEP(ehv[s]);
            #pragma unroll
            for (int ks = 0; ks < 4; ks++) KEEP(a[s][ks]);
        }
        if (c < 30) {
            #pragma unroll
            for (int ks = 0; ks < 4; ks++)
                bn2[ks] = *(const bf16x8*)(qbfp + ((size_t)((c + 2) * 4 + ks) * 64 + l) * 8);
            tn2 = thc[(c + 2) * 16 + (l & 15)];
        }
        f32x4 acc[4];
        #pragma unroll
        for (int s = 0; s < 4; s++)   // esq enters via the C operand
            acc[s] = __builtin_amdgcn_mfma_f32_16x16x32_bf16(a[s][0], bcur[0], ehv[s], 0, 0, 0);
        #pragma unroll
        for (int ks = 1; ks < 4; ks++)
            #pragma unroll
            for (int s = 0; s < 4; s++)
                acc[s] = __builtin_amdgcn_mfma_f32_16x16x32_bf16(a[s][ks], bcur[ks], acc[s], 0, 0, 0);
        uint32_t cl = 0;
        #pragma unroll
        for (int s = 0; s < 4; s++)
            #pragma unroll
            for (int r = 0; r < 4; r++)
                cl += (acc[s][r] < tc) ? 1u : 0u;   // esqh + dot < (thr-qsq)/2
        creg[c >> 2] += cl << (8 * (c & 3));
        tc = tn1; tn1 = tn2;
        #pragma unroll
        for (int ks = 0; ks < 4; ks++) { bcur[ks] = bn1[ks]; bn1[ks] = bn2[ks]; }
    }

    #pragma unroll
    for (int i = 0; i < 8; i++) {
        uint32_t x = creg[i];
        x += __shfl_xor(x, 16);
        x += __shfl_xor(x, 32);
        creg[i] = x;
    }
    if (l < 16) {
        #pragma unroll
        for (int c = 0; c < 32; c++)
            part[(size_t)bt * 512 + c * 16 + l] =
                (unsigned short)((creg[c >> 2] >> (8 * (c & 3))) & 0xffu);
    }
}

// Fallback path (round-6 proven) when ws is too small for part.
__global__ __launch_bounds__(128, 3) void k_count_fb(
    const float* __restrict__ ent,
    const unsigned short* __restrict__ qbf,
    const float* __restrict__ thc,
    int* __restrict__ cnt)
{
    int tid = threadIdx.x;
    int lane = tid & 63, wave = tid >> 6;
    int base = blockIdx.x * BM;
    int koff = (lane >> 4) * 8;
    int colq = wave * 256 + (lane & 15);
    const unsigned short* qb = qbf + (size_t)colq * DIM + koff;
    bf16x8 bcur[4], bnext[4];
    #pragma unroll
    for (int ks = 0; ks < 4; ks++) bcur[ks] = *(const bf16x8*)(qb + ks * 32);
    bf16x8 a[4][4];
    float hsq[4];
    #pragma unroll
    for (int s = 0; s < 4; s++) {
        int n = base + s * 16 + (lane & 15);
        bool valid = n < N_ENT;
        const float* rowp = ent + (size_t)(valid ? n : (N_ENT - 1)) * DIM + koff;
        float ss = 0.f;
        #pragma unroll
        for (int ks = 0; ks < 4; ks++) {
            float4 u0 = *(const float4*)(rowp + ks * 32);
            float4 u1 = *(const float4*)(rowp + ks * 32 + 4);
            ss += u0.x*u0.x + u0.y*u0.y + u0.z*u0.z + u0.w*u0.w
                + u1.x*u1.x + u1.y*u1.y + u1.z*u1.z + u1.w*u1.w;
            bf16x8 f;
            f[0]=(short)f2bf(u0.x); f[1]=(short)f2bf(u0.y); f[2]=(short)f2bf(u0.z); f[3]=(short)f2bf(u0.w);
            f[4]=(short)f2bf(u1.x); f[5]=(short)f2bf(u1.y); f[6]=(short)f2bf(u1.z); f[7]=(short)f2bf(u1.w);
            a[s][ks] = f; KEEP(a[s][ks]);
        }
        ss += __shfl_xor(ss, 16); ss += __shfl_xor(ss, 32);
        hsq[s] = valid ? ss * 0.5f : 1.5e38f;
    }
    float eh[4][4];
    #pragma unroll
    for (int s = 0; s < 4; s++)
        #pragma unroll
        for (int r = 0; r < 4; r++) { eh[s][r] = __shfl(hsq[s], (lane >> 4) * 4 + r); KEEP(eh[s][r]); }
    #pragma unroll
    for (int c = 0; c < 16; c++) {
        if (c < 15) {
            #pragma unroll
            for (int ks = 0; ks < 4; ks++)
                bnext[ks] = *(const bf16x8*)(qb + (size_t)(c + 1) * 16 * DIM + ks * 32);
        }
        float tcv = thc[colq + c * 16];
        f32x4 acc[4];
        #pragma unroll
        for (int s = 0; s < 4; s++) acc[s] = (f32x4){0.f, 0.f, 0.f, 0.f};
        #pragma unroll
        for (int ks = 0; ks < 4; ks++)
            #pragma unroll
            for (int s = 0; s < 4; s++)
                acc[s] = __builtin_amdgcn_mfma_f32_16x16x32_bf16(a[s][ks], bcur[ks], acc[s], 0, 0, 0);
        int cl = 0;
        #pragma unroll
        for (int s = 0; s < 4; s++)
            #pragma unroll
            for (int r = 0; r < 4; r++)
                cl += (acc[s][r] < tcv - eh[s][r]) ? 1 : 0;
        cl += __shfl_xor(cl, 16);
        cl += __shfl_xor(cl, 32);
        if (lane < 16) atomicAdd(&cnt[colq + c * 16], cl);
        #pragma unroll
        for (int ks = 0; ks < 4; ks++) bcur[ks] = bnext[ks];
    }
}

// Per (side,b)=key: strided sum of the part column (L2-hot), per-b match
// segment gather, dedup, exact fp32 recompute, rank = sum + 1 - adj.
__global__ __launch_bounds__(256) void k_adjust(
    const float* __restrict__ ent,
    const float* __restrict__ qall, const float* __restrict__ qsq, const float* __restrict__ thr,
    const int* __restrict__ cnt, const unsigned short* __restrict__ part, int use_part,
    const int* __restrict__ percnt, const int2* __restrict__ match,
    int* __restrict__ out)
{
    int key = blockIdx.x;
    int side = key >> 8, b = key & 255;
    int tid = threadIdx.x;
    __shared__ int ids[MCAP_B];
    __shared__ int nm;
    __shared__ int wsum[4];
    if (tid == 0) nm = 0;
    __syncthreads();

    int acc = 0;
    if (use_part) {
        for (int i = tid; i < NBT; i += 256)
            acc += part[(size_t)i * 512 + key];
    } else if (tid == 0) {
        acc = cnt[key];
    }

    int M = percnt[b];
    if (tid < M) {
        int2 e = match[b * MCAP_B + tid];
        if (e.x == side) { int p = atomicAdd(&nm, 1); ids[p] = e.y; }
    }
    __syncthreads();
    int mm = nm;
    const float* qv = qall + (size_t)key * DIM;
    float qq = qsq[key], th = thr[key];
    for (int i = tid; i < mm; i += 256) {
        int id = ids[i];
        bool dup = false;
        for (int j = 0; j < i; j++) if (ids[j] == id) { dup = true; break; }
        if (!dup) {
            const float* en = ent + (size_t)id * DIM;
            float es = 0.f, dot = 0.f;
            for (int d = 0; d < DIM; d++) { float x = en[d]; es += x * x; dot += x * qv[d]; }
            if (fmaxf(es + 2.f * dot + qq, 1e-12f) < th) acc--;
        }
    }
    #pragma unroll
    for (int off = 32; off; off >>= 1) acc += __shfl_xor(acc, off);
    int lane = tid & 63, wv = tid >> 6;
    if (lane == 0) wsum[wv] = acc;
    __syncthreads();
    if (tid == 0) out[key] = wsum[0] + wsum[1] + wsum[2] + wsum[3] + 1;
}

extern "C" void kernel_launch(void* const* d_in, const int* in_sizes, int n_in,
                              void* d_out, int out_size, void* d_ws, size_t ws_size,
                              hipStream_t stream)
{
    const float* ent   = (const float*)d_in[0];
    const float* rel   = (const float*)d_in[1];
    const int*   heads = (const int*)d_in[2];
    const int*   rels  = (const int*)d_in[3];
    const int*   tails = (const int*)d_in[4];
    const int*   fh    = (const int*)d_in[5];
    const int*   fr    = (const int*)d_in[6];
    const int*   ft    = (const int*)d_in[7];
    int* out = (int*)d_out;

    char* ws = (char*)d_ws;
    float* qall = (float*)(ws + WS_QALL);
    float* qsq  = (float*)(ws + WS_QSQ);
    float* thr  = (float*)(ws + WS_THR);
    float* thc  = (float*)(ws + WS_THC);
    int*   cnt  = (int*)(ws + WS_CNT);
    int*   percnt = (int*)(ws + WS_PERCNT);
    int2*  match  = (int2*)(ws + WS_MATCH);
    unsigned short* qbf   = (unsigned short*)(ws + WS_QBF);
    unsigned short* qbfp  = (unsigned short*)(ws + WS_QBFP);
    unsigned short* part  = (unsigned short*)(ws + WS_PART);

    int use_part = (ws_size >= (size_t)WS_NEED) ? 1 : 0;

    k_front<<<2 * BSZ, 256, 0, stream>>>(ent, rel, heads, rels, tails, fh, fr, ft,
                                         qall, qsq, thr, thc, cnt, qbf, qbfp,
                                         percnt, match);
    if (use_part)
        k_count<<<(NBT + 3) / 4, 256, 0, stream>>>(ent, qbfp, thc, part);
    else
        k_count_fb<<<NBT, 128, 0, stream>>>(ent, qbf, thc, cnt);
    k_adjust<<<2 * BSZ, 256, 0, stream>>>(ent, qall, qsq, thr, cnt, part, use_part,
                                          percnt, match, out);
}